// Round 1
// baseline (975.025 us; speedup 1.0000x reference)
//
#include <hip/hip_runtime.h>

#define B_TOT 1024   // BATCH * nbr = 64 * 16
#define L_DIM 64
#define K_DIM 32
#define U_DIM 4
#define IN1   64
#define IN2   8
#define OUT_K 32
#define EPS_BN 1e-5f

// ---------------------------------------------------------------------------
// Kernel 1: Hmk[b,c,l] = mean_k H[b,c,l,k], Hml[b,c,k] = mean_l H[b,c,l,k]
// where H[b, ri*4+u, l, k] = Hhat_{ri}[b, l, k, u]
// ---------------------------------------------------------------------------
__global__ __launch_bounds__(256) void hmeans_kernel(const float* __restrict__ Hr,
                                                     const float* __restrict__ Hi,
                                                     float* __restrict__ Hmk,
                                                     float* __restrict__ Hml) {
    __shared__ float tile[8192]; // one b's worth of one array: [l][k][u]
    int b = blockIdx.x;
    int tid = threadIdx.x;
    for (int ri = 0; ri < 2; ++ri) {
        const float* src = (ri == 0 ? Hr : Hi) + (size_t)b * 8192;
        const float4* src4 = (const float4*)src;
        float4* t4 = (float4*)tile;
        for (int j = tid; j < 2048; j += 256) t4[j] = src4[j];
        __syncthreads();
        {
            int l = tid >> 2, u = tid & 3;
            float s = 0.f;
            for (int k = 0; k < 32; ++k) s += tile[l * 128 + k * 4 + u];
            Hmk[(size_t)b * 512 + (ri * 4 + u) * 64 + l] = s * (1.0f / 32.0f);
        }
        if (tid < 128) {
            int k = tid >> 2, u = tid & 3;
            float s = 0.f;
            for (int l = 0; l < 64; ++l) s += tile[l * 128 + k * 4 + u];
            Hml[(size_t)b * 256 + (ri * 4 + u) * 32 + k] = s * (1.0f / 64.0f);
        }
        __syncthreads();
    }
}

// ---------------------------------------------------------------------------
// Hidden layer: new_AP = relu(2*Q1a@A_AP + 2*(Q2a@mean_k A_UE) + 0.1*P1a@Hmk)
//               new_UE = relu(2*Q1u@A_UE + 2*(Q2u@mean_l A_AP) + 0.1*P1u@Hml)
// plus per-channel sum/sumsq accumulation for BN (post-ReLU values).
// One block per b. stats layout: sumAP[64] sqAP[64] sumUE[64] sqUE[64]
// ---------------------------------------------------------------------------
__global__ __launch_bounds__(256) void layer_hidden_kernel(
    const float* __restrict__ Aap_in, const float* __restrict__ Aue_in,
    float* __restrict__ Aap_out, float* __restrict__ Aue_out,
    const float* __restrict__ Hmk, const float* __restrict__ Hml,
    const float* __restrict__ Q,   // Q1a | Q2a | Q1u | Q2u, each 64x64
    const float* __restrict__ P,   // P1a | P1u, each 64x8
    float* __restrict__ stats,
    int first) {
    __shared__ float sAP[64 * 65];
    __shared__ float sUE[64 * 33];
    __shared__ float sHmk[512];
    __shared__ float sHml[256];
    __shared__ float muAP[64], muUE[64], bAP[64], bUE[64];

    int b = blockIdx.x, tid = threadIdx.x;

    if (!first) {
        const float4* a4 = (const float4*)(Aap_in + (size_t)b * 4096);
        for (int j = tid; j < 1024; j += 256) {
            float4 v = a4[j];
            int i = j >> 4, l0 = (j & 15) * 4;
            float* d = &sAP[i * 65 + l0];
            d[0] = v.x; d[1] = v.y; d[2] = v.z; d[3] = v.w;
        }
        const float4* u4 = (const float4*)(Aue_in + (size_t)b * 2048);
        for (int j = tid; j < 512; j += 256) {
            float4 v = u4[j];
            int i = j >> 3, k0 = (j & 7) * 4;
            float* d = &sUE[i * 33 + k0];
            d[0] = v.x; d[1] = v.y; d[2] = v.z; d[3] = v.w;
        }
    } else {
        for (int j = tid; j < 64 * 65; j += 256) sAP[j] = 0.f;
        for (int j = tid; j < 64 * 33; j += 256) sUE[j] = 0.f;
    }
    {
        const float4* hk4 = (const float4*)(Hmk + (size_t)b * 512);
        for (int j = tid; j < 128; j += 256) ((float4*)sHmk)[j] = hk4[j];
        const float4* hl4 = (const float4*)(Hml + (size_t)b * 256);
        if (tid < 64) ((float4*)sHml)[tid] = hl4[tid];
    }
    __syncthreads();

    // spatial means of the input activations
    if (tid < 64) {
        float s = 0.f;
        for (int l = 0; l < 64; ++l) s += sAP[tid * 65 + l];
        muAP[tid] = s * (1.0f / 64.0f);
    } else if (tid < 128) {
        int i = tid - 64;
        float s = 0.f;
        for (int k = 0; k < 32; ++k) s += sUE[i * 33 + k];
        muUE[i] = s * (1.0f / 32.0f);
    }
    __syncthreads();

    // per-output bias terms from the Q2 (cross) paths
    if (tid < 64) {
        const float* Q2a = Q + 4096;
        float s = 0.f;
        for (int i = 0; i < 64; ++i) s += Q2a[tid * 64 + i] * muUE[i];
        bAP[tid] = 2.0f * s;
    } else if (tid < 128) {
        int o = tid - 64;
        const float* Q2u = Q + 3 * 4096;
        float s = 0.f;
        for (int i = 0; i < 64; ++i) s += Q2u[o * 64 + i] * muAP[i];
        bUE[o] = 2.0f * s;
    }
    __syncthreads();

    // AP outputs: 64 x 64, wave handles one o across l-lanes
    {
        int l = tid & 63, og = tid >> 6; // og in 0..3
        const float* Q1a = Q;
        const float* P1a = P;
        for (int m = 0; m < 16; ++m) {
            int o = og * 16 + m;
            float acc = bAP[o];
            for (int c = 0; c < 8; ++c) acc += 0.1f * P1a[o * 8 + c] * sHmk[c * 64 + l];
            if (!first) {
                float acc2 = 0.f;
                for (int i = 0; i < 64; ++i) acc2 += Q1a[o * 64 + i] * sAP[i * 65 + l];
                acc += 2.0f * acc2;
            }
            float v = fmaxf(acc, 0.f);
            Aap_out[(size_t)b * 4096 + o * 64 + l] = v;
            float s = v, sq = v * v;
            for (int w = 1; w < 64; w <<= 1) {
                s  += __shfl_xor(s, w);
                sq += __shfl_xor(sq, w);
            }
            if (l == 0) {
                atomicAdd(&stats[o], s);
                atomicAdd(&stats[64 + o], sq);
            }
        }
    }

    // UE outputs: 64 x 32, half-wave per o
    {
        int k = tid & 31, og = tid >> 5; // og in 0..7
        const float* Q1u = Q + 2 * 4096;
        const float* P1u = P + 512;
        for (int m = 0; m < 8; ++m) {
            int o = og * 8 + m;
            float acc = bUE[o];
            for (int c = 0; c < 8; ++c) acc += 0.1f * P1u[o * 8 + c] * sHml[c * 32 + k];
            if (!first) {
                float acc2 = 0.f;
                for (int i = 0; i < 64; ++i) acc2 += Q1u[o * 64 + i] * sUE[i * 33 + k];
                acc += 2.0f * acc2;
            }
            float v = fmaxf(acc, 0.f);
            Aue_out[(size_t)b * 2048 + o * 32 + k] = v;
            float s = v, sq = v * v;
            for (int w = 1; w < 32; w <<= 1) {
                s  += __shfl_xor(s, w);
                sq += __shfl_xor(sq, w);
            }
            if (k == 0) {
                atomicAdd(&stats[128 + o], s);
                atomicAdd(&stats[192 + o], sq);
            }
        }
    }
}

// ---------------------------------------------------------------------------
// BN finalize: scale/shift per channel. coef: scAP[64] shAP[64] scUE[64] shUE[64]
// ---------------------------------------------------------------------------
__global__ void bn_finalize_kernel(const float* __restrict__ stats,
                                   const float* __restrict__ gamma,
                                   const float* __restrict__ beta,
                                   float* __restrict__ coef) {
    int tid = threadIdx.x;
    if (tid < 64) {
        const float cnt = (float)(B_TOT * L_DIM);
        float m = stats[tid] / cnt;
        float var = stats[64 + tid] / cnt - m * m;
        float sc = gamma[tid] / sqrtf(var + EPS_BN);
        coef[tid] = sc;
        coef[64 + tid] = beta[tid] - m * sc;
    } else if (tid < 128) {
        int o = tid - 64;
        const float cnt = (float)(B_TOT * K_DIM);
        float m = stats[128 + o] / cnt;
        float var = stats[192 + o] / cnt - m * m;
        float sc = gamma[o] / sqrtf(var + EPS_BN);
        coef[128 + o] = sc;
        coef[192 + o] = beta[o] - m * sc;
    }
}

// ---------------------------------------------------------------------------
// BN apply (in place, affine per channel)
// ---------------------------------------------------------------------------
__global__ __launch_bounds__(256) void bn_apply_kernel(float* __restrict__ Aap,
                                                       float* __restrict__ Aue,
                                                       const float* __restrict__ coef) {
    int idx = blockIdx.x * 256 + threadIdx.x;
    int stride = gridDim.x * 256;
    float4* a4 = (float4*)Aap;
    const int nAP4 = B_TOT * 1024;
    for (int j = idx; j < nAP4; j += stride) {
        int ch = (j >> 4) & 63;
        float sc = coef[ch], sh = coef[64 + ch];
        float4 v = a4[j];
        v.x = v.x * sc + sh; v.y = v.y * sc + sh;
        v.z = v.z * sc + sh; v.w = v.w * sc + sh;
        a4[j] = v;
    }
    float4* u4 = (float4*)Aue;
    const int nUE4 = B_TOT * 512;
    for (int j = idx; j < nUE4; j += stride) {
        int ch = (j >> 3) & 63;
        float sc = coef[128 + ch], sh = coef[192 + ch];
        float4 v = u4[j];
        v.x = v.x * sc + sh; v.y = v.y * sc + sh;
        v.z = v.z * sc + sh; v.w = v.w * sc + sh;
        u4[j] = v;
    }
}

// ---------------------------------------------------------------------------
// Output layer (AP path only, out=32 channels, no act/BN)
// ---------------------------------------------------------------------------
__global__ __launch_bounds__(256) void layer_out_kernel(
    const float* __restrict__ Aap_in, const float* __restrict__ Aue_in,
    const float* __restrict__ Hmk,
    const float* __restrict__ Qo,  // Q1a | Q2a | Q1u | Q2u, each 32x64
    const float* __restrict__ Po,  // P1a | P1u, each 32x8
    float* __restrict__ V) {
    __shared__ float sAP[64 * 65];
    __shared__ float sUE[64 * 33];
    __shared__ float sHmk[512];
    __shared__ float muUE[64], bAP[32];

    int b = blockIdx.x, tid = threadIdx.x;
    {
        const float4* a4 = (const float4*)(Aap_in + (size_t)b * 4096);
        for (int j = tid; j < 1024; j += 256) {
            float4 v = a4[j];
            int i = j >> 4, l0 = (j & 15) * 4;
            float* d = &sAP[i * 65 + l0];
            d[0] = v.x; d[1] = v.y; d[2] = v.z; d[3] = v.w;
        }
        const float4* u4 = (const float4*)(Aue_in + (size_t)b * 2048);
        for (int j = tid; j < 512; j += 256) {
            float4 v = u4[j];
            int i = j >> 3, k0 = (j & 7) * 4;
            float* d = &sUE[i * 33 + k0];
            d[0] = v.x; d[1] = v.y; d[2] = v.z; d[3] = v.w;
        }
        const float4* hk4 = (const float4*)(Hmk + (size_t)b * 512);
        for (int j = tid; j < 128; j += 256) ((float4*)sHmk)[j] = hk4[j];
    }
    __syncthreads();
    if (tid < 64) {
        float s = 0.f;
        for (int k = 0; k < 32; ++k) s += sUE[tid * 33 + k];
        muUE[tid] = s * (1.0f / 32.0f);
    }
    __syncthreads();
    if (tid < 32) {
        const float* Q2o = Qo + OUT_K * 64; // second matrix
        float s = 0.f;
        for (int i = 0; i < 64; ++i) s += Q2o[tid * 64 + i] * muUE[i];
        bAP[tid] = 2.0f * s;
    }
    __syncthreads();
    {
        int l = tid & 63, og = tid >> 6; // 0..3
        for (int m = 0; m < 8; ++m) {
            int o = og * 8 + m;
            float acc = bAP[o];
            for (int c = 0; c < 8; ++c) acc += 0.1f * Po[o * 8 + c] * sHmk[c * 64 + l];
            float acc2 = 0.f;
            for (int i = 0; i < 64; ++i) acc2 += Qo[o * 64 + i] * sAP[i * 65 + l];
            acc += 2.0f * acc2;
            V[(size_t)b * 2048 + o * 64 + l] = acc;
        }
    }
}

// ---------------------------------------------------------------------------
// Final: Phat1[bb,r,l,k] = V[b,k,l]; norm over l; Fhat = Vhat * Phat1/norm*sqrt(L)
// ---------------------------------------------------------------------------
__global__ __launch_bounds__(256) void finalize_kernel(const float* __restrict__ V,
                                                       const float* __restrict__ Vhat,
                                                       float* __restrict__ out) {
    __shared__ float sV[32 * 65];
    __shared__ float inv[32];
    int b = blockIdx.x, tid = threadIdx.x;
    const float4* v4 = (const float4*)(V + (size_t)b * 2048);
    for (int j = tid; j < 512; j += 256) {
        float4 x = v4[j];
        int k = j >> 4, l0 = (j & 15) * 4;
        float* d = &sV[k * 65 + l0];
        d[0] = x.x; d[1] = x.y; d[2] = x.z; d[3] = x.w;
    }
    __syncthreads();
    if (tid < 32) {
        float s = 0.f;
        for (int l = 0; l < 64; ++l) { float x = sV[tid * 65 + l]; s += x * x; }
        inv[tid] = 8.0f / sqrtf(s); // sqrt(L)=8
    }
    __syncthreads();
    const float4* vh4 = (const float4*)(Vhat + (size_t)b * 8192);
    float4* o4 = (float4*)out + (size_t)b * 2048;
    for (int j = tid; j < 2048; j += 256) {
        int l = j >> 5, k = j & 31;
        float p = sV[k * 65 + l] * inv[k];
        float4 x = vh4[j];
        x.x *= p; x.y *= p; x.z *= p; x.w *= p;
        o4[j] = x;
    }
}

// ---------------------------------------------------------------------------
extern "C" void kernel_launch(void* const* d_in, const int* in_sizes, int n_in,
                              void* d_out, int out_size, void* d_ws, size_t ws_size,
                              hipStream_t stream) {
    const float* Hr        = (const float*)d_in[0];
    const float* Hi        = (const float*)d_in[1];
    const float* Vhat      = (const float*)d_in[2];
    const float* Qs_hidden = (const float*)d_in[3];
    const float* Ps_hidden = (const float*)d_in[4];
    const float* Qs_out    = (const float*)d_in[5];
    const float* Ps_out    = (const float*)d_in[6];
    const float* bn_gamma  = (const float*)d_in[7];
    const float* bn_beta   = (const float*)d_in[8];
    float* out = (float*)d_out;

    float* ws   = (float*)d_ws;
    float* Hmk  = ws;                    // 1024*512
    float* Hml  = Hmk + 524288;          // 1024*256
    float* AapA = Hml + 262144;          // 1024*4096
    float* AueA = AapA + 4194304;        // 1024*2048
    float* AapB = AueA + 2097152;        // 1024*4096
    float* AueB = AapB + 4194304;        // 1024*2048
    float* stats = AueB + 2097152;       // 256
    float* coef  = stats + 256;          // 256
    float* V     = AapA;                 // alias: set A dead after layer 1 reads it

    hipLaunchKernelGGL(hmeans_kernel, dim3(B_TOT), dim3(256), 0, stream, Hr, Hi, Hmk, Hml);

    // hidden layer 0 (inputs are zero)
    hipMemsetAsync(stats, 0, 256 * sizeof(float), stream);
    hipLaunchKernelGGL(layer_hidden_kernel, dim3(B_TOT), dim3(256), 0, stream,
                       (const float*)nullptr, (const float*)nullptr, AapA, AueA,
                       Hmk, Hml, Qs_hidden, Ps_hidden, stats, 1);
    hipLaunchKernelGGL(bn_finalize_kernel, dim3(1), dim3(128), 0, stream,
                       stats, bn_gamma, bn_beta, coef);
    hipLaunchKernelGGL(bn_apply_kernel, dim3(2048), dim3(256), 0, stream, AapA, AueA, coef);

    // hidden layer 1
    hipMemsetAsync(stats, 0, 256 * sizeof(float), stream);
    hipLaunchKernelGGL(layer_hidden_kernel, dim3(B_TOT), dim3(256), 0, stream,
                       AapA, AueA, AapB, AueB,
                       Hmk, Hml, Qs_hidden + 4 * 4096, Ps_hidden + 2 * 512, stats, 0);
    hipLaunchKernelGGL(bn_finalize_kernel, dim3(1), dim3(128), 0, stream,
                       stats, bn_gamma + 64, bn_beta + 64, coef);
    hipLaunchKernelGGL(bn_apply_kernel, dim3(2048), dim3(256), 0, stream, AapB, AueB, coef);

    // output layer + normalization/scale
    hipLaunchKernelGGL(layer_out_kernel, dim3(B_TOT), dim3(256), 0, stream,
                       AapB, AueB, Hmk, Qs_out, Ps_out, V);
    hipLaunchKernelGGL(finalize_kernel, dim3(B_TOT), dim3(256), 0, stream, V, Vhat, out);
}

// Round 2
// 161.214 us; speedup vs baseline: 6.0480x; 6.0480x over previous
//
#include <hip/hip_runtime.h>

#define B_TOT 1024   // BATCH * nbr = 64 * 16
#define L_DIM 64
#define K_DIM 32
#define U_DIM 4
#define IN1   64
#define IN2   8
#define OUT_K 32
#define EPS_BN 1e-5f

// ---------------------------------------------------------------------------
// Kernel 1: Hmk[b,c,l] = mean_k H[b,c,l,k], Hml[b,c,k] = mean_l H[b,c,l,k]
// where H[b, ri*4+u, l, k] = Hhat_{ri}[b, l, k, u]
// ---------------------------------------------------------------------------
__global__ __launch_bounds__(256) void hmeans_kernel(const float* __restrict__ Hr,
                                                     const float* __restrict__ Hi,
                                                     float* __restrict__ Hmk,
                                                     float* __restrict__ Hml) {
    __shared__ float tile[8192]; // one b's worth of one array: [l][k][u]
    int b = blockIdx.x;
    int tid = threadIdx.x;
    for (int ri = 0; ri < 2; ++ri) {
        const float* src = (ri == 0 ? Hr : Hi) + (size_t)b * 8192;
        const float4* src4 = (const float4*)src;
        float4* t4 = (float4*)tile;
        for (int j = tid; j < 2048; j += 256) t4[j] = src4[j];
        __syncthreads();
        {
            int l = tid >> 2, u = tid & 3;
            float s = 0.f;
            for (int k = 0; k < 32; ++k) s += tile[l * 128 + k * 4 + u];
            Hmk[(size_t)b * 512 + (ri * 4 + u) * 64 + l] = s * (1.0f / 32.0f);
        }
        if (tid < 128) {
            int k = tid >> 2, u = tid & 3;
            float s = 0.f;
            for (int l = 0; l < 64; ++l) s += tile[l * 128 + k * 4 + u];
            Hml[(size_t)b * 256 + (ri * 4 + u) * 32 + k] = s * (1.0f / 64.0f);
        }
        __syncthreads();
    }
}

// ---------------------------------------------------------------------------
// Hidden layer: new_AP = relu(2*Q1a@A_AP + 2*(Q2a@mean_k A_UE) + 0.1*P1a@Hmk)
//               new_UE = relu(2*Q1u@A_UE + 2*(Q2u@mean_l A_AP) + 0.1*P1u@Hml)
// BN affine of the PREVIOUS layer is applied while staging A into LDS (coefIn).
// Per-channel BN partial sums (post-ReLU) are written per block:
//   statsS[ch*1024 + b], statsQ[ch*1024 + b], ch: 0..63 AP, 64..127 UE
// ---------------------------------------------------------------------------
__global__ __launch_bounds__(256) void layer_hidden_kernel(
    const float* __restrict__ Aap_in, const float* __restrict__ Aue_in,
    float* __restrict__ Aap_out, float* __restrict__ Aue_out,
    const float* __restrict__ Hmk, const float* __restrict__ Hml,
    const float* __restrict__ Q,   // Q1a | Q2a | Q1u | Q2u, each 64x64
    const float* __restrict__ P,   // P1a | P1u, each 64x8
    const float* __restrict__ coefIn, // scAP[64] shAP[64] scUE[64] shUE[64] (null if first)
    float* __restrict__ statsS, float* __restrict__ statsQ,
    int first) {
    __shared__ float sAP[64 * 65];
    __shared__ float sUE[64 * 33];
    __shared__ float sHmk[512];
    __shared__ float sHml[256];
    __shared__ float muAP[64], muUE[64], bAP[64], bUE[64];

    int b = blockIdx.x, tid = threadIdx.x;

    if (!first) {
        const float4* a4 = (const float4*)(Aap_in + (size_t)b * 4096);
        for (int j = tid; j < 1024; j += 256) {
            float4 v = a4[j];
            int i = j >> 4, l0 = (j & 15) * 4;
            float sc = coefIn[i], sh = coefIn[64 + i];
            float* d = &sAP[i * 65 + l0];
            d[0] = v.x * sc + sh; d[1] = v.y * sc + sh;
            d[2] = v.z * sc + sh; d[3] = v.w * sc + sh;
        }
        const float4* u4 = (const float4*)(Aue_in + (size_t)b * 2048);
        for (int j = tid; j < 512; j += 256) {
            float4 v = u4[j];
            int i = j >> 3, k0 = (j & 7) * 4;
            float sc = coefIn[128 + i], sh = coefIn[192 + i];
            float* d = &sUE[i * 33 + k0];
            d[0] = v.x * sc + sh; d[1] = v.y * sc + sh;
            d[2] = v.z * sc + sh; d[3] = v.w * sc + sh;
        }
    } else {
        for (int j = tid; j < 64 * 65; j += 256) sAP[j] = 0.f;
        for (int j = tid; j < 64 * 33; j += 256) sUE[j] = 0.f;
    }
    {
        const float4* hk4 = (const float4*)(Hmk + (size_t)b * 512);
        for (int j = tid; j < 128; j += 256) ((float4*)sHmk)[j] = hk4[j];
        const float4* hl4 = (const float4*)(Hml + (size_t)b * 256);
        if (tid < 64) ((float4*)sHml)[tid] = hl4[tid];
    }
    __syncthreads();

    // spatial means of the (BN-applied) input activations
    if (tid < 64) {
        float s = 0.f;
        for (int l = 0; l < 64; ++l) s += sAP[tid * 65 + l];
        muAP[tid] = s * (1.0f / 64.0f);
    } else if (tid < 128) {
        int i = tid - 64;
        float s = 0.f;
        for (int k = 0; k < 32; ++k) s += sUE[i * 33 + k];
        muUE[i] = s * (1.0f / 32.0f);
    }
    __syncthreads();

    // per-output bias terms from the Q2 (cross) paths
    if (tid < 64) {
        const float* Q2a = Q + 4096;
        float s = 0.f;
        for (int i = 0; i < 64; ++i) s += Q2a[tid * 64 + i] * muUE[i];
        bAP[tid] = 2.0f * s;
    } else if (tid < 128) {
        int o = tid - 64;
        const float* Q2u = Q + 3 * 4096;
        float s = 0.f;
        for (int i = 0; i < 64; ++i) s += Q2u[o * 64 + i] * muAP[i];
        bUE[o] = 2.0f * s;
    }
    __syncthreads();

    // AP outputs: 64 x 64, wave handles one o across l-lanes
    {
        int l = tid & 63, og = tid >> 6; // og in 0..3
        const float* Q1a = Q;
        const float* P1a = P;
        for (int m = 0; m < 16; ++m) {
            int o = og * 16 + m;
            float acc = bAP[o];
            for (int c = 0; c < 8; ++c) acc += 0.1f * P1a[o * 8 + c] * sHmk[c * 64 + l];
            if (!first) {
                float acc2 = 0.f;
                for (int i = 0; i < 64; ++i) acc2 += Q1a[o * 64 + i] * sAP[i * 65 + l];
                acc += 2.0f * acc2;
            }
            float v = fmaxf(acc, 0.f);
            Aap_out[(size_t)b * 4096 + o * 64 + l] = v;
            float s = v, sq = v * v;
            for (int w = 1; w < 64; w <<= 1) {
                s  += __shfl_xor(s, w);
                sq += __shfl_xor(sq, w);
            }
            if (l == 0) {
                statsS[o * 1024 + b] = s;
                statsQ[o * 1024 + b] = sq;
            }
        }
    }

    // UE outputs: 64 x 32, half-wave per o
    {
        int k = tid & 31, og = tid >> 5; // og in 0..7
        const float* Q1u = Q + 2 * 4096;
        const float* P1u = P + 512;
        for (int m = 0; m < 8; ++m) {
            int o = og * 8 + m;
            float acc = bUE[o];
            for (int c = 0; c < 8; ++c) acc += 0.1f * P1u[o * 8 + c] * sHml[c * 32 + k];
            if (!first) {
                float acc2 = 0.f;
                for (int i = 0; i < 64; ++i) acc2 += Q1u[o * 64 + i] * sUE[i * 33 + k];
                acc += 2.0f * acc2;
            }
            float v = fmaxf(acc, 0.f);
            Aue_out[(size_t)b * 2048 + o * 32 + k] = v;
            float s = v, sq = v * v;
            for (int w = 1; w < 32; w <<= 1) {
                s  += __shfl_xor(s, w);
                sq += __shfl_xor(sq, w);
            }
            if (k == 0) {
                statsS[(64 + o) * 1024 + b] = s;
                statsQ[(64 + o) * 1024 + b] = sq;
            }
        }
    }
}

// ---------------------------------------------------------------------------
// BN finalize: one block per channel (128 blocks). Reduces 1024 per-block
// partials, computes scale/shift: coef = scAP[64] shAP[64] scUE[64] shUE[64]
// ---------------------------------------------------------------------------
__global__ __launch_bounds__(256) void bn_finalize_kernel(
    const float* __restrict__ statsS, const float* __restrict__ statsQ,
    const float* __restrict__ gamma, const float* __restrict__ beta,
    float* __restrict__ coef) {
    __shared__ float redS[4], redQ[4];
    int ch = blockIdx.x;   // 0..127
    int tid = threadIdx.x;
    float s = 0.f, q = 0.f;
    for (int j = tid; j < 1024; j += 256) {
        s += statsS[ch * 1024 + j];
        q += statsQ[ch * 1024 + j];
    }
    for (int w = 1; w < 64; w <<= 1) {
        s += __shfl_xor(s, w);
        q += __shfl_xor(q, w);
    }
    int wave = tid >> 6, lane = tid & 63;
    if (lane == 0) { redS[wave] = s; redQ[wave] = q; }
    __syncthreads();
    if (tid == 0) {
        s = redS[0] + redS[1] + redS[2] + redS[3];
        q = redQ[0] + redQ[1] + redQ[2] + redQ[3];
        bool ap = ch < 64;
        int o = ap ? ch : ch - 64;
        float cnt = ap ? (float)(B_TOT * L_DIM) : (float)(B_TOT * K_DIM);
        float m = s / cnt;
        float var = q / cnt - m * m;
        float sc = gamma[o] / sqrtf(var + EPS_BN);
        if (ap) { coef[o] = sc;       coef[64 + o] = beta[o] - m * sc; }
        else    { coef[128 + o] = sc; coef[192 + o] = beta[o] - m * sc; }
    }
}

// ---------------------------------------------------------------------------
// Output layer (AP path only, out=32 channels, no act/BN). Applies coefIn
// (BN of last hidden layer) while staging A.
// ---------------------------------------------------------------------------
__global__ __launch_bounds__(256) void layer_out_kernel(
    const float* __restrict__ Aap_in, const float* __restrict__ Aue_in,
    const float* __restrict__ Hmk,
    const float* __restrict__ Qo,  // Q1a | Q2a | Q1u | Q2u, each 32x64
    const float* __restrict__ Po,  // P1a | P1u, each 32x8
    const float* __restrict__ coefIn,
    float* __restrict__ V) {
    __shared__ float sAP[64 * 65];
    __shared__ float sUE[64 * 33];
    __shared__ float sHmk[512];
    __shared__ float muUE[64], bAP[32];

    int b = blockIdx.x, tid = threadIdx.x;
    {
        const float4* a4 = (const float4*)(Aap_in + (size_t)b * 4096);
        for (int j = tid; j < 1024; j += 256) {
            float4 v = a4[j];
            int i = j >> 4, l0 = (j & 15) * 4;
            float sc = coefIn[i], sh = coefIn[64 + i];
            float* d = &sAP[i * 65 + l0];
            d[0] = v.x * sc + sh; d[1] = v.y * sc + sh;
            d[2] = v.z * sc + sh; d[3] = v.w * sc + sh;
        }
        const float4* u4 = (const float4*)(Aue_in + (size_t)b * 2048);
        for (int j = tid; j < 512; j += 256) {
            float4 v = u4[j];
            int i = j >> 3, k0 = (j & 7) * 4;
            float sc = coefIn[128 + i], sh = coefIn[192 + i];
            float* d = &sUE[i * 33 + k0];
            d[0] = v.x * sc + sh; d[1] = v.y * sc + sh;
            d[2] = v.z * sc + sh; d[3] = v.w * sc + sh;
        }
        const float4* hk4 = (const float4*)(Hmk + (size_t)b * 512);
        for (int j = tid; j < 128; j += 256) ((float4*)sHmk)[j] = hk4[j];
    }
    __syncthreads();
    if (tid < 64) {
        float s = 0.f;
        for (int k = 0; k < 32; ++k) s += sUE[tid * 33 + k];
        muUE[tid] = s * (1.0f / 32.0f);
    }
    __syncthreads();
    if (tid < 32) {
        const float* Q2o = Qo + OUT_K * 64; // second matrix
        float s = 0.f;
        for (int i = 0; i < 64; ++i) s += Q2o[tid * 64 + i] * muUE[i];
        bAP[tid] = 2.0f * s;
    }
    __syncthreads();
    {
        int l = tid & 63, og = tid >> 6; // 0..3
        for (int m = 0; m < 8; ++m) {
            int o = og * 8 + m;
            float acc = bAP[o];
            for (int c = 0; c < 8; ++c) acc += 0.1f * Po[o * 8 + c] * sHmk[c * 64 + l];
            float acc2 = 0.f;
            for (int i = 0; i < 64; ++i) acc2 += Qo[o * 64 + i] * sAP[i * 65 + l];
            acc += 2.0f * acc2;
            V[(size_t)b * 2048 + o * 64 + l] = acc;
        }
    }
}

// ---------------------------------------------------------------------------
// Final: Phat1[bb,r,l,k] = V[b,k,l]; norm over l; Fhat = Vhat * Phat1/norm*sqrt(L)
// ---------------------------------------------------------------------------
__global__ __launch_bounds__(256) void finalize_kernel(const float* __restrict__ V,
                                                       const float* __restrict__ Vhat,
                                                       float* __restrict__ out) {
    __shared__ float sV[32 * 65];
    __shared__ float inv[32];
    int b = blockIdx.x, tid = threadIdx.x;
    const float4* v4 = (const float4*)(V + (size_t)b * 2048);
    for (int j = tid; j < 512; j += 256) {
        float4 x = v4[j];
        int k = j >> 4, l0 = (j & 15) * 4;
        float* d = &sV[k * 65 + l0];
        d[0] = x.x; d[1] = x.y; d[2] = x.z; d[3] = x.w;
    }
    __syncthreads();
    if (tid < 32) {
        float s = 0.f;
        for (int l = 0; l < 64; ++l) { float x = sV[tid * 65 + l]; s += x * x; }
        inv[tid] = 8.0f / sqrtf(s); // sqrt(L)=8
    }
    __syncthreads();
    const float4* vh4 = (const float4*)(Vhat + (size_t)b * 8192);
    float4* o4 = (float4*)out + (size_t)b * 2048;
    for (int j = tid; j < 2048; j += 256) {
        int l = j >> 5, k = j & 31;
        float p = sV[k * 65 + l] * inv[k];
        float4 x = vh4[j];
        x.x *= p; x.y *= p; x.z *= p; x.w *= p;
        o4[j] = x;
    }
}

// ---------------------------------------------------------------------------
extern "C" void kernel_launch(void* const* d_in, const int* in_sizes, int n_in,
                              void* d_out, int out_size, void* d_ws, size_t ws_size,
                              hipStream_t stream) {
    const float* Hr        = (const float*)d_in[0];
    const float* Hi        = (const float*)d_in[1];
    const float* Vhat      = (const float*)d_in[2];
    const float* Qs_hidden = (const float*)d_in[3];
    const float* Ps_hidden = (const float*)d_in[4];
    const float* Qs_out    = (const float*)d_in[5];
    const float* Ps_out    = (const float*)d_in[6];
    const float* bn_gamma  = (const float*)d_in[7];
    const float* bn_beta   = (const float*)d_in[8];
    float* out = (float*)d_out;

    float* ws     = (float*)d_ws;
    float* Hmk    = ws;                    // 1024*512
    float* Hml    = Hmk + 524288;          // 1024*256
    float* AapA   = Hml + 262144;          // 1024*4096
    float* AueA   = AapA + 4194304;        // 1024*2048
    float* AapB   = AueA + 2097152;        // 1024*4096
    float* AueB   = AapB + 4194304;        // 1024*2048
    float* statsS = AueB + 2097152;        // 128*1024
    float* statsQ = statsS + 131072;       // 128*1024
    float* coefA  = statsQ + 131072;       // 256
    float* coefB  = coefA + 256;           // 256
    float* V      = AapA;                  // alias: AapA dead after layer 1 reads it

    hipLaunchKernelGGL(hmeans_kernel, dim3(B_TOT), dim3(256), 0, stream, Hr, Hi, Hmk, Hml);

    // hidden layer 0 (inputs are zero)
    hipLaunchKernelGGL(layer_hidden_kernel, dim3(B_TOT), dim3(256), 0, stream,
                       (const float*)nullptr, (const float*)nullptr, AapA, AueA,
                       Hmk, Hml, Qs_hidden, Ps_hidden,
                       (const float*)nullptr, statsS, statsQ, 1);
    hipLaunchKernelGGL(bn_finalize_kernel, dim3(128), dim3(256), 0, stream,
                       statsS, statsQ, bn_gamma, bn_beta, coefA);

    // hidden layer 1 (applies coefA on load)
    hipLaunchKernelGGL(layer_hidden_kernel, dim3(B_TOT), dim3(256), 0, stream,
                       AapA, AueA, AapB, AueB,
                       Hmk, Hml, Qs_hidden + 4 * 4096, Ps_hidden + 2 * 512,
                       coefA, statsS, statsQ, 0);
    hipLaunchKernelGGL(bn_finalize_kernel, dim3(128), dim3(256), 0, stream,
                       statsS, statsQ, bn_gamma + 64, bn_beta + 64, coefB);

    // output layer (applies coefB on load) + normalization/scale
    hipLaunchKernelGGL(layer_out_kernel, dim3(B_TOT), dim3(256), 0, stream,
                       AapB, AueB, Hmk, Qs_out, Ps_out, coefB, V);
    hipLaunchKernelGGL(finalize_kernel, dim3(B_TOT), dim3(256), 0, stream, V, Vhat, out);
}